// Round 1
// baseline (164.282 us; speedup 1.0000x reference)
//
#include <hip/hip_runtime.h>
#include <math.h>

#define BS 4
#define LPTS 128
#define CH 3
#define IMG 256
#define NPIX (IMG*IMG)

__device__ __forceinline__ bool lessVI(float v1, int i1, float v2, int i2) {
    return (v1 < v2) || (v1 == v2 && i1 < i2);
}

// One block per (b,l). 256 threads. Finds the 8 smallest sim indices.
__global__ __launch_bounds__(256)
void topk_kernel(const float* __restrict__ pred,
                 const float* __restrict__ imgs,
                 int* __restrict__ out_idx) {
    const int m = blockIdx.x;          // m = b*L + l
    const int b = m >> 7;
    const int l = m & (LPTS - 1);
    // reshape quirk: pooled[b,l] comes from flat row n = l*bs + b of
    // predictions viewed as (bs*L, 2)
    const int n  = l * BS + b;
    const int pb = n >> 7;
    const int pl = n & (LPTS - 1);
    const float px = pred[(pb * LPTS + pl) * 8 + 0];
    const float py = pred[(pb * LPTS + pl) * 8 + 1];
    const int ix = (int)fminf(fmaxf(rintf(px * 256.0f - 0.5f), 0.0f), 255.0f);
    const int iy = (int)fminf(fmaxf(rintf(py * 256.0f - 0.5f), 0.0f), 255.0f);

    const float* img = imgs + b * CH * NPIX;
    const int pc = iy * IMG + ix;
    const float c0 = img[pc];
    const float c1 = img[NPIX + pc];
    const float c2 = img[2 * NPIX + pc];

    // per-thread top-8 (ascending), (val, idx) lexicographic
    float bv[8];
    int   bi[8];
#pragma unroll
    for (int k = 0; k < 8; ++k) { bv[k] = 3.0e38f; bi[k] = 0x7FFFFFFF; }

    const float4* i0 = (const float4*)img;
    const float4* i1 = (const float4*)(img + NPIX);
    const float4* i2 = (const float4*)(img + 2 * NPIX);

    for (int q = threadIdx.x; q < NPIX / 4; q += 256) {
        const float4 a0 = i0[q];
        const float4 a1 = i1[q];
        const float4 a2 = i2[q];
        const int p = q * 4;
        float s;
#define TRY_INSERT(sv, pv)                                                    \
        do {                                                                  \
            if (lessVI((sv), (pv), bv[7], bi[7])) {                           \
                bv[7] = (sv); bi[7] = (pv);                                   \
                _Pragma("unroll")                                             \
                for (int k = 7; k > 0; --k) {                                 \
                    if (lessVI(bv[k], bi[k], bv[k-1], bi[k-1])) {             \
                        float tv = bv[k]; bv[k] = bv[k-1]; bv[k-1] = tv;      \
                        int   ti = bi[k]; bi[k] = bi[k-1]; bi[k-1] = ti;      \
                    }                                                         \
                }                                                             \
            }                                                                 \
        } while (0)
        s = fabsf(a0.x - c0) + fabsf(a1.x - c1) + fabsf(a2.x - c2); TRY_INSERT(s, p + 0);
        s = fabsf(a0.y - c0) + fabsf(a1.y - c1) + fabsf(a2.y - c2); TRY_INSERT(s, p + 1);
        s = fabsf(a0.z - c0) + fabsf(a1.z - c1) + fabsf(a2.z - c2); TRY_INSERT(s, p + 2);
        s = fabsf(a0.w - c0) + fabsf(a1.w - c1) + fabsf(a2.w - c2); TRY_INSERT(s, p + 3);
    }

    // wave-level merge: 6 butterfly steps across 64 lanes.
    // Partner list is sorted asc; w[k] = minpair(v[k], ov[7-k]) gives the 8
    // smallest of 16 as a bitonic sequence; then 3-stage bitonic sort network.
#pragma unroll
    for (int off = 1; off < 64; off <<= 1) {
        float ov[8]; int oi[8];
#pragma unroll
        for (int k = 0; k < 8; ++k) {
            ov[k] = __shfl_xor(bv[k], off, 64);
            oi[k] = __shfl_xor(bi[k], off, 64);
        }
        float w[8]; int wi[8];
#pragma unroll
        for (int k = 0; k < 8; ++k) {
            if (lessVI(bv[k], bi[k], ov[7 - k], oi[7 - k])) { w[k] = bv[k];     wi[k] = bi[k]; }
            else                                            { w[k] = ov[7 - k]; wi[k] = oi[7 - k]; }
        }
#define CE(a, c)                                                              \
        do {                                                                  \
            if (lessVI(w[c], wi[c], w[a], wi[a])) {                           \
                float tv = w[a]; w[a] = w[c]; w[c] = tv;                      \
                int   ti = wi[a]; wi[a] = wi[c]; wi[c] = ti;                  \
            }                                                                 \
        } while (0)
        CE(0, 4); CE(1, 5); CE(2, 6); CE(3, 7);
        CE(0, 2); CE(1, 3); CE(4, 6); CE(5, 7);
        CE(0, 1); CE(2, 3); CE(4, 5); CE(6, 7);
#undef CE
#pragma unroll
        for (int k = 0; k < 8; ++k) { bv[k] = w[k]; bi[k] = wi[k]; }
    }

    // cross-wave merge (4 waves) via LDS; thread 0 does 4-way sorted merge
    __shared__ float sv[4][8];
    __shared__ int   si[4][8];
    const int lane = threadIdx.x & 63;
    const int wid  = threadIdx.x >> 6;
    if (lane == 0) {
#pragma unroll
        for (int k = 0; k < 8; ++k) { sv[wid][k] = bv[k]; si[wid][k] = bi[k]; }
    }
    __syncthreads();
    if (threadIdx.x == 0) {
        int ptr[4] = {0, 0, 0, 0};
        int* o = out_idx + m * 8;
        for (int r = 0; r < 8; ++r) {
            int   best = 0;
            float bvv = sv[0][ptr[0]];
            int   bii = si[0][ptr[0]];
            for (int w = 1; w < 4; ++w) {
                float vv = sv[w][ptr[w]];
                int   ii = si[w][ptr[w]];
                if (lessVI(vv, ii, bvv, bii)) { best = w; bvv = vv; bii = ii; }
            }
            o[r] = bii;
            ptr[best]++;
        }
    }
}

// Single block, 512 threads: one per (b,l). Loss over l>=1.
__global__ __launch_bounds__(512)
void loss_kernel(const float* __restrict__ pred,
                 const int* __restrict__ idxs,
                 float* __restrict__ out) {
    __shared__ float red[512];
    const int t = threadIdx.x;
    const int b = t >> 7;
    const int l = t & (LPTS - 1);
    float v = 0.0f;
    if (l >= 1) {
        const float px = pred[(b * LPTS + l) * 8 + 0];
        const float py = pred[(b * LPTS + l) * 8 + 1];
        const int* q = idxs + (b * LPTS + (l - 1)) * 8;
        float best = 3.0e38f;
#pragma unroll
        for (int k = 0; k < 8; ++k) {
            const int id = q[k];
            const float tx = (float)(id & (IMG - 1)) * (1.0f / IMG);
            const float ty = (float)(id >> 8)        * (1.0f / IMG);
            const float dx = px - tx;
            const float dy = py - ty;
            best = fminf(best, sqrtf(dx * dx + dy * dy));
        }
        v = best;
    }
    red[t] = v;
    __syncthreads();
    for (int s = 256; s > 0; s >>= 1) {
        if (t < s) red[t] += red[t + s];
        __syncthreads();
    }
    if (t == 0) out[0] = red[0] * (1.0f / (BS * (LPTS - 1)));
}

extern "C" void kernel_launch(void* const* d_in, const int* in_sizes, int n_in,
                              void* d_out, int out_size, void* d_ws, size_t ws_size,
                              hipStream_t stream) {
    const float* pred = (const float*)d_in[0];   // (4,128,8) f32
    const float* imgs = (const float*)d_in[1];   // (4,3,256,256) f32
    float* out = (float*)d_out;                  // scalar f32
    int* idx_ws = (int*)d_ws;                    // 512*8 ints = 16 KB

    hipLaunchKernelGGL(topk_kernel, dim3(BS * LPTS), dim3(256), 0, stream,
                       pred, imgs, idx_ws);
    hipLaunchKernelGGL(loss_kernel, dim3(1), dim3(512), 0, stream,
                       pred, idx_ws, out);
}

// Round 3
// 48.609 us; speedup vs baseline: 3.3797x; 3.3797x over previous
//
#include <hip/hip_runtime.h>
#include <math.h>

#define BS 4
#define LQ 128
#define IMG 256
#define NPIX (IMG*IMG)
#define CAP 2048

__device__ __forceinline__ bool lessVI(float v1, int i1, float v2, int i2) {
    return (v1 < v2) || (v1 == v2 && i1 < i2);
}

// 256 blocks, 512 threads. Block owns (batch b, queries l0=2*qp, l1=2*qp+1).
// Phase A: pooled colors + sampled threshold tau per query (8th-smallest of a
//          4096-sample subset; guaranteed >= true 8th-smallest over all pixels).
// Phase B: full scan, append candidates with s <= tau to LDS lists (~128 exp).
// Phase C: exact lexicographic top-8 per query from candidate list.
__global__ __launch_bounds__(512)
void scan_kernel(const float* __restrict__ pred,
                 const float* __restrict__ imgs,
                 int* __restrict__ out_idx) {
    __shared__ float pool[2][3];
    __shared__ float ltau[2];
    __shared__ int   cnt[2];
    __shared__ float swv[8][8];
    __shared__ float lv[2][CAP];
    __shared__ int   li[2][CAP];

    const int bid = blockIdx.x;
    // XCD swizzle: 2 XCD slots per batch so each XCD's L2 holds one image.
    const int b  = (bid & 7) >> 1;
    const int qp = (bid >> 3) | ((bid & 1) << 5);   // query pair in [0,64)
    const int tid  = threadIdx.x;
    const int qsel = tid >> 8;      // which of the 2 queries this thread samples
    const int st   = tid & 255;
    const int l    = qp * 2 + qsel;

    // pooled color: reshape quirk -> flat row n = l*BS + b of predictions(bs*L,2)
    const int n  = l * BS + b;
    const int pb = n >> 7;
    const int pl = n & (LQ - 1);
    const float px = pred[(pb * LQ + pl) * 8 + 0];
    const float py = pred[(pb * LQ + pl) * 8 + 1];
    const int ix = (int)fminf(fmaxf(rintf(px * 256.0f - 0.5f), 0.0f), 255.0f);
    const int iy = (int)fminf(fmaxf(rintf(py * 256.0f - 0.5f), 0.0f), 255.0f);
    const float* img = imgs + b * 3 * NPIX;
    const int pc = iy * IMG + ix;
    const float c0 = img[pc];
    const float c1 = img[NPIX + pc];
    const float c2 = img[2 * NPIX + pc];
    if (st == 0) {
        pool[qsel][0] = c0; pool[qsel][1] = c1; pool[qsel][2] = c2;
    }
    if (tid < 2) cnt[tid] = 0;

    // ---- Phase A: sample every 16th pixel (4096 samples), per-thread top-8
    float tb[8];
#pragma unroll
    for (int k = 0; k < 8; ++k) tb[k] = 3.0e38f;
    for (int j = 0; j < 16; ++j) {
        const int p = (st + j * 256) * 16;
        const float a0 = img[p];
        const float a1 = img[NPIX + p];
        const float a2 = img[2 * NPIX + p];
        const float s = fabsf(a0 - c0) + fabsf(a1 - c1) + fabsf(a2 - c2);
        if (s < tb[7]) {
            tb[7] = s;
#pragma unroll
            for (int k = 7; k > 0; --k) {
                if (tb[k] < tb[k - 1]) { float t = tb[k]; tb[k] = tb[k - 1]; tb[k - 1] = t; }
            }
        }
    }
    // wave bitonic merge, values only
#pragma unroll
    for (int off = 1; off < 64; off <<= 1) {
        float ov[8];
#pragma unroll
        for (int k = 0; k < 8; ++k) ov[k] = __shfl_xor(tb[k], off, 64);
        float w[8];
#pragma unroll
        for (int k = 0; k < 8; ++k) w[k] = fminf(tb[k], ov[7 - k]);
#define CEV(a, c) do { float lo = fminf(w[a], w[c]); float hi = fmaxf(w[a], w[c]); w[a] = lo; w[c] = hi; } while (0)
        CEV(0, 4); CEV(1, 5); CEV(2, 6); CEV(3, 7);
        CEV(0, 2); CEV(1, 3); CEV(4, 6); CEV(5, 7);
        CEV(0, 1); CEV(2, 3); CEV(4, 5); CEV(6, 7);
#undef CEV
#pragma unroll
        for (int k = 0; k < 8; ++k) tb[k] = w[k];
    }
    const int wid  = tid >> 6;
    const int lane = tid & 63;
    if (lane == 0) {
#pragma unroll
        for (int k = 0; k < 8; ++k) swv[wid][k] = tb[k];
    }
    __syncthreads();
    if ((tid & 255) == 0) {      // tid 0 -> q0 (waves 0..3), tid 256 -> q1 (waves 4..7)
        const int q = tid >> 8;
        const int base = q * 4;
        int ptr[4] = {0, 0, 0, 0};
        float last = 0.0f;
        for (int r = 0; r < 8; ++r) {
            int best = 0; float bvv = swv[base][ptr[0]];
            for (int w = 1; w < 4; ++w) {
                float vv = swv[base + w][ptr[w]];
                if (vv < bvv) { best = w; bvv = vv; }
            }
            last = bvv;
            ptr[best]++;
        }
        ltau[q] = last;     // 8th smallest sampled value: guaranteed >= true 8th smallest
    }
    __syncthreads();

    // ---- Phase B: full scan, append candidates
    const float t0 = ltau[0], t1 = ltau[1];
    const float q00 = pool[0][0], q01 = pool[0][1], q02 = pool[0][2];
    const float q10 = pool[1][0], q11 = pool[1][1], q12 = pool[1][2];
    const float4* i0 = (const float4*)img;
    const float4* i1 = (const float4*)(img + NPIX);
    const float4* i2 = (const float4*)(img + 2 * NPIX);

    for (int q4 = tid; q4 < NPIX / 4; q4 += 512) {
        const float4 a0 = i0[q4];
        const float4 a1 = i1[q4];
        const float4 a2 = i2[q4];
        const int p = q4 * 4;
#define PROC(vx, vy, vz, pix)                                                  \
        do {                                                                   \
            const float s0 = fabsf((vx) - q00) + fabsf((vy) - q01) + fabsf((vz) - q02); \
            if (s0 <= t0) {                                                    \
                const int pos = atomicAdd(&cnt[0], 1);                         \
                if (pos < CAP) { lv[0][pos] = s0; li[0][pos] = (pix); }        \
            }                                                                  \
            const float s1 = fabsf((vx) - q10) + fabsf((vy) - q11) + fabsf((vz) - q12); \
            if (s1 <= t1) {                                                    \
                const int pos = atomicAdd(&cnt[1], 1);                         \
                if (pos < CAP) { lv[1][pos] = s1; li[1][pos] = (pix); }        \
            }                                                                  \
        } while (0)
        PROC(a0.x, a1.x, a2.x, p + 0);
        PROC(a0.y, a1.y, a2.y, p + 1);
        PROC(a0.z, a1.z, a2.z, p + 2);
        PROC(a0.w, a1.w, a2.w, p + 3);
#undef PROC
    }
    __syncthreads();

    // ---- Phase C: exact top-8 from candidate list (wave 0 -> q0, wave 4 -> q1)
    if ((wid & 3) == 0) {
        const int q = wid >> 2;
        const int nels = min(cnt[q], CAP);
        float bv[8]; int bi[8];
#pragma unroll
        for (int k = 0; k < 8; ++k) { bv[k] = 3.0e38f; bi[k] = 0x7FFFFFFF; }
        for (int c = lane; c < nels; c += 64) {
            const float v = lv[q][c];
            const int  id = li[q][c];
            if (lessVI(v, id, bv[7], bi[7])) {
                bv[7] = v; bi[7] = id;
#pragma unroll
                for (int k = 7; k > 0; --k) {
                    if (lessVI(bv[k], bi[k], bv[k - 1], bi[k - 1])) {
                        float tv = bv[k]; bv[k] = bv[k - 1]; bv[k - 1] = tv;
                        int   ti = bi[k]; bi[k] = bi[k - 1]; bi[k - 1] = ti;
                    }
                }
            }
        }
        // wave bitonic merge with (val, idx)
#pragma unroll
        for (int off = 1; off < 64; off <<= 1) {
            float ov[8]; int oi[8];
#pragma unroll
            for (int k = 0; k < 8; ++k) {
                ov[k] = __shfl_xor(bv[k], off, 64);
                oi[k] = __shfl_xor(bi[k], off, 64);
            }
            float w[8]; int wi[8];
#pragma unroll
            for (int k = 0; k < 8; ++k) {
                if (lessVI(bv[k], bi[k], ov[7 - k], oi[7 - k])) { w[k] = bv[k];     wi[k] = bi[k]; }
                else                                            { w[k] = ov[7 - k]; wi[k] = oi[7 - k]; }
            }
#define CE(a, c)                                                               \
            do {                                                               \
                if (lessVI(w[c], wi[c], w[a], wi[a])) {                        \
                    float tv = w[a]; w[a] = w[c]; w[c] = tv;                   \
                    int   ti = wi[a]; wi[a] = wi[c]; wi[c] = ti;               \
                }                                                              \
            } while (0)
            CE(0, 4); CE(1, 5); CE(2, 6); CE(3, 7);
            CE(0, 2); CE(1, 3); CE(4, 6); CE(5, 7);
            CE(0, 1); CE(2, 3); CE(4, 5); CE(6, 7);
#undef CE
#pragma unroll
            for (int k = 0; k < 8; ++k) { bv[k] = w[k]; bi[k] = wi[k]; }
        }
        if (lane == 0) {
            const int mq = b * LQ + qp * 2 + q;
            int* o = out_idx + mq * 8;
#pragma unroll
            for (int k = 0; k < 8; ++k) o[k] = bi[k];
        }
    }
}

// Single block, 512 threads: one per (b,l). Loss over l>=1.
__global__ __launch_bounds__(512)
void loss_kernel(const float* __restrict__ pred,
                 const int* __restrict__ idxs,
                 float* __restrict__ out) {
    __shared__ float red[512];
    const int t = threadIdx.x;
    const int b = t >> 7;
    const int l = t & (LQ - 1);
    float v = 0.0f;
    if (l >= 1) {
        const float px = pred[(b * LQ + l) * 8 + 0];
        const float py = pred[(b * LQ + l) * 8 + 1];
        const int* q = idxs + (b * LQ + (l - 1)) * 8;
        float best = 3.0e38f;
#pragma unroll
        for (int k = 0; k < 8; ++k) {
            const int id = q[k];
            const float tx = (float)(id & (IMG - 1)) * (1.0f / IMG);
            const float ty = (float)(id >> 8)        * (1.0f / IMG);
            const float dx = px - tx;
            const float dy = py - ty;
            best = fminf(best, sqrtf(dx * dx + dy * dy));
        }
        v = best;
    }
    red[t] = v;
    __syncthreads();
    for (int s = 256; s > 0; s >>= 1) {
        if (t < s) red[t] += red[t + s];
        __syncthreads();
    }
    if (t == 0) out[0] = red[0] * (1.0f / (BS * (LQ - 1)));
}

extern "C" void kernel_launch(void* const* d_in, const int* in_sizes, int n_in,
                              void* d_out, int out_size, void* d_ws, size_t ws_size,
                              hipStream_t stream) {
    const float* pred = (const float*)d_in[0];   // (4,128,8) f32
    const float* imgs = (const float*)d_in[1];   // (4,3,256,256) f32
    float* out = (float*)d_out;                  // scalar f32
    int* idx_ws = (int*)d_ws;                    // 512*8 ints = 16 KB

    hipLaunchKernelGGL(scan_kernel, dim3(256), dim3(512), 0, stream,
                       pred, imgs, idx_ws);
    hipLaunchKernelGGL(loss_kernel, dim3(1), dim3(512), 0, stream,
                       pred, idx_ws, out);
}

// Round 4
// 41.761 us; speedup vs baseline: 3.9339x; 1.1640x over previous
//
#include <hip/hip_runtime.h>
#include <math.h>

#define BS 4
#define LQ 128
#define IMG 256
#define NPIX (IMG*IMG)
#define NSLICE 4
#define SLICE_PIX (NPIX/NSLICE)     // 16384
#define SLICE_F4  (SLICE_PIX/4)     // 4096
#define CAP 512

__device__ __forceinline__ bool lessVI(float v1, int i1, float v2, int i2) {
    return (v1 < v2) || (v1 == v2 && i1 < i2);
}

// in-thread merge of two sorted-ascending (val,idx) 8-lists -> sorted 8
// smallest of the 16 (bitonic minpair + 3-stage sort network, static idx)
#define CE8(WV, WI, a, c)                                                     \
    do {                                                                      \
        if (lessVI((WV)[c], (WI)[c], (WV)[a], (WI)[a])) {                     \
            float tv_ = (WV)[a]; (WV)[a] = (WV)[c]; (WV)[c] = tv_;            \
            int   ti_ = (WI)[a]; (WI)[a] = (WI)[c]; (WI)[c] = ti_;            \
        }                                                                     \
    } while (0)

#define MERGE8(AV, AI, BV, BI, OV, OI)                                        \
    do {                                                                      \
        _Pragma("unroll")                                                     \
        for (int k_ = 0; k_ < 8; ++k_) {                                      \
            if (lessVI((AV)[k_], (AI)[k_], (BV)[7-k_], (BI)[7-k_])) {         \
                (OV)[k_] = (AV)[k_]; (OI)[k_] = (AI)[k_];                     \
            } else { (OV)[k_] = (BV)[7-k_]; (OI)[k_] = (BI)[7-k_]; }          \
        }                                                                     \
        CE8(OV, OI, 0, 4); CE8(OV, OI, 1, 5); CE8(OV, OI, 2, 6); CE8(OV, OI, 3, 7); \
        CE8(OV, OI, 0, 2); CE8(OV, OI, 1, 3); CE8(OV, OI, 4, 6); CE8(OV, OI, 5, 7); \
        CE8(OV, OI, 0, 1); CE8(OV, OI, 2, 3); CE8(OV, OI, 4, 5); CE8(OV, OI, 6, 7); \
    } while (0)

// 1024 blocks x 512 threads. Block owns (batch b, query pair qp, slice sl).
// Phase A: pooled colors + per-slice sampled tau (8th smallest of a 4096-of-
//          16384 coalesced sample; tau >= slice's true 8th smallest).
// Phase B: scan slice, append candidates with s <= tau (exp ~32, CAP 512).
// Phase C: exact lexicographic top-8 per query per slice -> ws (val+idx).
__global__ __launch_bounds__(512)
void scan_kernel(const float* __restrict__ pred,
                 const float* __restrict__ imgs,
                 float* __restrict__ wsv,
                 int* __restrict__ wsi) {
    __shared__ float pool[2][3];
    __shared__ float ltau[2];
    __shared__ int   cnt[2];
    __shared__ float swv[8][8];
    __shared__ float lv[2][CAP];
    __shared__ int   li[2][CAP];

    const int bid = blockIdx.x;
    // XCD swizzle: 2 XCD slots per batch so each XCD's L2 holds one image.
    const int b  = (bid & 7) >> 1;
    const int u  = bid >> 3;                        // [0,128)
    const int sl = u & (NSLICE - 1);                // slice
    const int qp = (u >> 2) | ((bid & 1) << 5);     // query pair in [0,64)
    const int tid  = threadIdx.x;
    const int qsel = tid >> 8;                      // which query this thread samples
    const int st   = tid & 255;
    const int l    = qp * 2 + qsel;

    // pooled color: reshape quirk -> flat row n = l*BS + b of predictions(bs*L,2)
    const int n  = l * BS + b;
    const int pb = n >> 7;
    const int pl = n & (LQ - 1);
    const float px = pred[(pb * LQ + pl) * 8 + 0];
    const float py = pred[(pb * LQ + pl) * 8 + 1];
    const int ix = (int)fminf(fmaxf(rintf(px * 256.0f - 0.5f), 0.0f), 255.0f);
    const int iy = (int)fminf(fmaxf(rintf(py * 256.0f - 0.5f), 0.0f), 255.0f);
    const float* img = imgs + b * 3 * NPIX;
    const int pc = iy * IMG + ix;
    const float c0 = img[pc];
    const float c1 = img[NPIX + pc];
    const float c2 = img[2 * NPIX + pc];
    if (st == 0) {
        pool[qsel][0] = c0; pool[qsel][1] = c1; pool[qsel][2] = c2;
    }
    if (tid < 2) cnt[tid] = 0;

    // ---- Phase A: coalesced sample, 16 chunks of 256 contiguous pixels
    float tb[8];
#pragma unroll
    for (int k = 0; k < 8; ++k) tb[k] = 3.0e38f;
#pragma unroll 4
    for (int j = 0; j < 16; ++j) {
        const int p = sl * SLICE_PIX + j * 1024 + st;
        const float a0 = img[p];
        const float a1 = img[NPIX + p];
        const float a2 = img[2 * NPIX + p];
        const float s = fabsf(a0 - c0) + fabsf(a1 - c1) + fabsf(a2 - c2);
        if (s < tb[7]) {
            tb[7] = s;
#pragma unroll
            for (int k = 7; k > 0; --k) {
                if (tb[k] < tb[k - 1]) { float t = tb[k]; tb[k] = tb[k - 1]; tb[k - 1] = t; }
            }
        }
    }
    // wave bitonic merge, values only
#pragma unroll
    for (int off = 1; off < 64; off <<= 1) {
        float ov[8];
#pragma unroll
        for (int k = 0; k < 8; ++k) ov[k] = __shfl_xor(tb[k], off, 64);
        float w[8];
#pragma unroll
        for (int k = 0; k < 8; ++k) w[k] = fminf(tb[k], ov[7 - k]);
#define CEV(a, c) do { float lo = fminf(w[a], w[c]); float hi = fmaxf(w[a], w[c]); w[a] = lo; w[c] = hi; } while (0)
        CEV(0, 4); CEV(1, 5); CEV(2, 6); CEV(3, 7);
        CEV(0, 2); CEV(1, 3); CEV(4, 6); CEV(5, 7);
        CEV(0, 1); CEV(2, 3); CEV(4, 5); CEV(6, 7);
#undef CEV
#pragma unroll
        for (int k = 0; k < 8; ++k) tb[k] = w[k];
    }
    const int wid  = tid >> 6;
    const int lane = tid & 63;
    if (lane == 0) {
#pragma unroll
        for (int k = 0; k < 8; ++k) swv[wid][k] = tb[k];
    }
    __syncthreads();
    if ((tid & 255) == 0) {      // tid 0 -> q0 (waves 0..3), tid 256 -> q1 (waves 4..7)
        const int q = tid >> 8;
        const int base = q * 4;
        int ptr[4] = {0, 0, 0, 0};
        float last = 0.0f;
        for (int r = 0; r < 8; ++r) {
            int best = 0; float bvv = swv[base][ptr[0]];
            for (int w = 1; w < 4; ++w) {
                float vv = swv[base + w][ptr[w]];
                if (vv < bvv) { best = w; bvv = vv; }
            }
            last = bvv;
            ptr[best]++;
        }
        ltau[q] = last;     // 8th smallest sampled value >= slice's true 8th smallest
    }
    __syncthreads();

    // ---- Phase B: scan slice, append candidates
    const float t0 = ltau[0], t1 = ltau[1];
    const float q00 = pool[0][0], q01 = pool[0][1], q02 = pool[0][2];
    const float q10 = pool[1][0], q11 = pool[1][1], q12 = pool[1][2];
    const float4* i0 = (const float4*)img;
    const float4* i1 = (const float4*)(img + NPIX);
    const float4* i2 = (const float4*)(img + 2 * NPIX);

    const int base4 = sl * SLICE_F4;
#pragma unroll 2
    for (int it = 0; it < SLICE_F4 / 512; ++it) {
        const int q4 = base4 + it * 512 + tid;
        const float4 a0 = i0[q4];
        const float4 a1 = i1[q4];
        const float4 a2 = i2[q4];
        const int p = q4 * 4;
#define PROC(vx, vy, vz, pix)                                                  \
        do {                                                                   \
            const float s0 = fabsf((vx) - q00) + fabsf((vy) - q01) + fabsf((vz) - q02); \
            if (s0 <= t0) {                                                    \
                const int pos = atomicAdd(&cnt[0], 1);                         \
                if (pos < CAP) { lv[0][pos] = s0; li[0][pos] = (pix); }        \
            }                                                                  \
            const float s1 = fabsf((vx) - q10) + fabsf((vy) - q11) + fabsf((vz) - q12); \
            if (s1 <= t1) {                                                    \
                const int pos = atomicAdd(&cnt[1], 1);                         \
                if (pos < CAP) { lv[1][pos] = s1; li[1][pos] = (pix); }        \
            }                                                                  \
        } while (0)
        PROC(a0.x, a1.x, a2.x, p + 0);
        PROC(a0.y, a1.y, a2.y, p + 1);
        PROC(a0.z, a1.z, a2.z, p + 2);
        PROC(a0.w, a1.w, a2.w, p + 3);
#undef PROC
    }
    __syncthreads();

    // ---- Phase C: exact top-8 from candidates (wave 0 -> q0, wave 4 -> q1)
    if ((wid & 3) == 0) {
        const int q = wid >> 2;
        const int nels = min(cnt[q], CAP);
        float bv[8]; int bi[8];
#pragma unroll
        for (int k = 0; k < 8; ++k) { bv[k] = 3.0e38f; bi[k] = 0x7FFFFFFF; }
        for (int c = lane; c < nels; c += 64) {
            const float v = lv[q][c];
            const int  id = li[q][c];
            if (lessVI(v, id, bv[7], bi[7])) {
                bv[7] = v; bi[7] = id;
#pragma unroll
                for (int k = 7; k > 0; --k) {
                    if (lessVI(bv[k], bi[k], bv[k - 1], bi[k - 1])) {
                        float tv = bv[k]; bv[k] = bv[k - 1]; bv[k - 1] = tv;
                        int   ti = bi[k]; bi[k] = bi[k - 1]; bi[k - 1] = ti;
                    }
                }
            }
        }
        // wave bitonic merge with (val, idx)
#pragma unroll
        for (int off = 1; off < 64; off <<= 1) {
            float ov[8]; int oi[8];
#pragma unroll
            for (int k = 0; k < 8; ++k) {
                ov[k] = __shfl_xor(bv[k], off, 64);
                oi[k] = __shfl_xor(bi[k], off, 64);
            }
            float w[8]; int wi[8];
#pragma unroll
            for (int k = 0; k < 8; ++k) {
                if (lessVI(bv[k], bi[k], ov[7 - k], oi[7 - k])) { w[k] = bv[k];     wi[k] = bi[k]; }
                else                                            { w[k] = ov[7 - k]; wi[k] = oi[7 - k]; }
            }
            CE8(w, wi, 0, 4); CE8(w, wi, 1, 5); CE8(w, wi, 2, 6); CE8(w, wi, 3, 7);
            CE8(w, wi, 0, 2); CE8(w, wi, 1, 3); CE8(w, wi, 4, 6); CE8(w, wi, 5, 7);
            CE8(w, wi, 0, 1); CE8(w, wi, 2, 3); CE8(w, wi, 4, 5); CE8(w, wi, 6, 7);
#pragma unroll
            for (int k = 0; k < 8; ++k) { bv[k] = w[k]; bi[k] = wi[k]; }
        }
        if (lane == 0) {
            const int mq = b * LQ + qp * 2 + q;
            const int slot = mq * (NSLICE * 8) + sl * 8;
#pragma unroll
            for (int k = 0; k < 8; ++k) { wsv[slot + k] = bv[k]; wsi[slot + k] = bi[k]; }
        }
    }
}

// Single block, 512 threads: one per (b,l). Merge 4 slice lists exactly,
// then min distance over the true top-8; loss over l>=1.
__global__ __launch_bounds__(512)
void loss_kernel(const float* __restrict__ pred,
                 const float* __restrict__ wsv,
                 const int* __restrict__ wsi,
                 float* __restrict__ out) {
    __shared__ float red[512];
    const int t = threadIdx.x;
    const int b = t >> 7;
    const int l = t & (LQ - 1);
    float v = 0.0f;
    if (l >= 1) {
        const int mq = b * LQ + (l - 1);
        float av[4][8]; int ai[4][8];
#pragma unroll
        for (int s = 0; s < 4; ++s) {
#pragma unroll
            for (int k = 0; k < 8; ++k) {
                av[s][k] = wsv[mq * 32 + s * 8 + k];
                ai[s][k] = wsi[mq * 32 + s * 8 + k];
            }
        }
        float m0v[8]; int m0i[8];
        float m1v[8]; int m1i[8];
        float fv[8];  int fi[8];
        MERGE8(av[0], ai[0], av[1], ai[1], m0v, m0i);
        MERGE8(av[2], ai[2], av[3], ai[3], m1v, m1i);
        MERGE8(m0v, m0i, m1v, m1i, fv, fi);

        const float px = pred[(b * LQ + l) * 8 + 0];
        const float py = pred[(b * LQ + l) * 8 + 1];
        float best = 3.0e38f;
#pragma unroll
        for (int k = 0; k < 8; ++k) {
            const int id = fi[k];
            const float tx = (float)(id & (IMG - 1)) * (1.0f / IMG);
            const float ty = (float)(id >> 8)        * (1.0f / IMG);
            const float dx = px - tx;
            const float dy = py - ty;
            best = fminf(best, sqrtf(dx * dx + dy * dy));
        }
        v = best;
    }
    red[t] = v;
    __syncthreads();
    for (int s = 256; s > 0; s >>= 1) {
        if (t < s) red[t] += red[t + s];
        __syncthreads();
    }
    if (t == 0) out[0] = red[0] * (1.0f / (BS * (LQ - 1)));
}

extern "C" void kernel_launch(void* const* d_in, const int* in_sizes, int n_in,
                              void* d_out, int out_size, void* d_ws, size_t ws_size,
                              hipStream_t stream) {
    const float* pred = (const float*)d_in[0];   // (4,128,8) f32
    const float* imgs = (const float*)d_in[1];   // (4,3,256,256) f32
    float* out = (float*)d_out;                  // scalar f32
    float* wsv = (float*)d_ws;                               // 512*32 floats
    int*   wsi = (int*)((char*)d_ws + 512 * 32 * sizeof(float)); // 512*32 ints

    hipLaunchKernelGGL(scan_kernel, dim3(BS * 64 * NSLICE), dim3(512), 0, stream,
                       pred, imgs, wsv, wsi);
    hipLaunchKernelGGL(loss_kernel, dim3(1), dim3(512), 0, stream,
                       pred, wsv, wsi, out);
}